// Round 1
// baseline (234.745 us; speedup 1.0000x reference)
//
#include <hip/hip_runtime.h>
#include <math.h>

// LayerNorm_v2: B=8, S=4096, D=1024, f32 in / f32 out.
// Reference quirks replicated:
//  - stats from batch 0 only, broadcast over all batches
//  - "buggy Welford": mean_k=(mean_{k-1}+d_k)/k ; var += (d_k-mean_k)^2 ; var/=(D-1)
#define BB 8
#define SS 4096
#define DD 1024
#define EPSF 1e-5f

// Native vector type for nontemporal builtins.
typedef float f32x4 __attribute__((ext_vector_type(4)));

// ---------------------------------------------------------------------------
// Kernel 1: stats + batch-0 normalize, one wave per row.
// The recurrence forgets history factorially:
//   mean_j = arr[j-1]/j + arr[j-2]/(j(j-1)) + arr[j-3]/(j(j-1)(j-2)) + ...
// Lane L seeds mean_{16L} with a 6-term Horner series, then runs its 16
// recurrence steps exactly. Butterfly-reduce var so ALL lanes hold it, then
// normalize the row straight out of registers (batch 0 is never re-read).
// ---------------------------------------------------------------------------
__global__ __launch_bounds__(64) void stats_norm0_kernel(
    const float* __restrict__ x,
    const float* __restrict__ alpha,
    const float* __restrict__ beta,
    float* __restrict__ out,
    float* __restrict__ mean_out,
    float* __restrict__ rstd_out)
{
    const int row = blockIdx.x;           // 0..4095 (batch 0 rows)
    const int L   = threadIdx.x;          // 0..63; lane L owns k in [16L+1, 16L+16]
    const float4* __restrict__ rowp =
        reinterpret_cast<const float4*>(x) + (size_t)row * (DD / 4);

    // Own 16 floats: float4 indices 4L..4L+3.
    const float4 a0 = rowp[4 * L + 0];
    const float4 a1 = rowp[4 * L + 1];
    const float4 a2 = rowp[4 * L + 2];
    const float4 a3 = rowp[4 * L + 3];
    const float d[16] = { a0.x, a0.y, a0.z, a0.w,  a1.x, a1.y, a1.z, a1.w,
                          a2.x, a2.y, a2.z, a2.w,  a3.x, a3.y, a3.z, a3.w };

    // Seed mean_{16L} from the 6 preceding elements (closed-form series).
    float m = 0.0f;
    if (L > 0) {
        const float4 p0 = rowp[4 * L - 2];   // floats 16L-8 .. 16L-5
        const float4 p1 = rowp[4 * L - 1];   // floats 16L-4 .. 16L-1
        const float jf = (float)(16 * L);
        float acc = p0.z;                                          // arr[j-6]
        acc = fmaf(acc, __builtin_amdgcn_rcpf(jf - 5.0f), p0.w);   // arr[j-5] + acc/(j-5)
        acc = fmaf(acc, __builtin_amdgcn_rcpf(jf - 4.0f), p1.x);
        acc = fmaf(acc, __builtin_amdgcn_rcpf(jf - 3.0f), p1.y);
        acc = fmaf(acc, __builtin_amdgcn_rcpf(jf - 2.0f), p1.z);
        acc = fmaf(acc, __builtin_amdgcn_rcpf(jf - 1.0f), p1.w);
        m = acc * __builtin_amdgcn_rcpf(jf);
    }

    // 16 exact recurrence steps.
    float var = 0.0f;
    const float base = (float)(16 * L);
#pragma unroll
    for (int t = 0; t < 16; ++t) {
        const float rk = __builtin_amdgcn_rcpf(base + (float)(t + 1));  // 1/k
        m = (m + d[t]) * rk;
        const float df = d[t] - m;
        var = fmaf(df, df, var);
    }

    // Butterfly reduction: every lane ends with the full var sum.
#pragma unroll
    for (int off = 32; off >= 1; off >>= 1) var += __shfl_xor(var, off, 64);
    const float mean_final = __shfl(m, 63, 64);      // broadcast lane 63's mean
    const float r = rsqrtf(var * (1.0f / 1023.0f) + EPSF);

    if (L == 0) {
        mean_out[row] = mean_final;
        rstd_out[row] = r;
    }

    // Normalize this row directly from registers (no x re-read for batch 0).
    const float4* __restrict__ alpha4 = reinterpret_cast<const float4*>(alpha);
    const float4* __restrict__ beta4  = reinterpret_cast<const float4*>(beta);
    f32x4* __restrict__ outp = reinterpret_cast<f32x4*>(out) + (size_t)row * (DD / 4);
#pragma unroll
    for (int q = 0; q < 4; ++q) {
        const float4 av = alpha4[4 * L + q];
        const float4 bv = beta4[4 * L + q];
        f32x4 o;
        o.x = fmaf(av.x * (d[4 * q + 0] - mean_final), r, bv.x);
        o.y = fmaf(av.y * (d[4 * q + 1] - mean_final), r, bv.y);
        o.z = fmaf(av.z * (d[4 * q + 2] - mean_final), r, bv.z);
        o.w = fmaf(av.w * (d[4 * q + 3] - mean_final), r, bv.w);
        __builtin_nontemporal_store(o, outp + 4 * L + q);
    }
}

// ---------------------------------------------------------------------------
// Kernel 2: streaming normalize for batches 1..7 (28672 rows).
// Grid-stride by chunk: 2048 blocks (exactly 8 blocks/CU) x 256 threads.
// Each thread keeps a FIXED float4 column slot -> alpha/beta stay in
// registers across all 14 rows. Depth-2 software pipeline: the next row's
// load is issued before the current row's store, so every wave always has
// a VMEM op in flight (the old one-load-one-store-per-thread version had
// zero ILP). Nontemporal on the big x/out streams.
// ---------------------------------------------------------------------------
#define NBLK 2048
#define RPB  14   // (BB-1)*SS / NBLK = 28672/2048

__global__ __launch_bounds__(256) void norm_rest_kernel(
    const float* __restrict__ x,
    const float* __restrict__ alpha,
    const float* __restrict__ beta,
    const float* __restrict__ meanp,
    const float* __restrict__ rstdp,
    float* __restrict__ out)
{
    const int tid = threadIdx.x;                  // fixed float4 slot in row
    const float4 av = reinterpret_cast<const float4*>(alpha)[tid];
    const float4 bv = reinterpret_cast<const float4*>(beta)[tid];

    const f32x4* __restrict__ xp = reinterpret_cast<const f32x4*>(x);
    f32x4* __restrict__ op       = reinterpret_cast<f32x4*>(out);

    const int row0 = SS + blockIdx.x * RPB;       // first row of this chunk
    size_t i4 = (size_t)row0 * (DD / 4) + tid;

    // Prologue: load row0.
    f32x4 cur = __builtin_nontemporal_load(xp + i4);
    float m = meanp[row0 & (SS - 1)];
    float r = rstdp[row0 & (SS - 1)];

#pragma unroll
    for (int j = 0; j < RPB - 1; ++j) {
        const int  rown = row0 + j + 1;
        const size_t i4n = i4 + (DD / 4);
        // Issue next row's load before storing current row.
        const f32x4 nxt = __builtin_nontemporal_load(xp + i4n);
        const float mn  = meanp[rown & (SS - 1)];
        const float rn  = rstdp[rown & (SS - 1)];

        f32x4 o;
        o.x = fmaf(av.x * (cur.x - m), r, bv.x);
        o.y = fmaf(av.y * (cur.y - m), r, bv.y);
        o.z = fmaf(av.z * (cur.z - m), r, bv.z);
        o.w = fmaf(av.w * (cur.w - m), r, bv.w);
        __builtin_nontemporal_store(o, op + i4);

        cur = nxt; m = mn; r = rn; i4 = i4n;
    }

    // Epilogue: last row.
    f32x4 o;
    o.x = fmaf(av.x * (cur.x - m), r, bv.x);
    o.y = fmaf(av.y * (cur.y - m), r, bv.y);
    o.z = fmaf(av.z * (cur.z - m), r, bv.z);
    o.w = fmaf(av.w * (cur.w - m), r, bv.w);
    __builtin_nontemporal_store(o, op + i4);
}

extern "C" void kernel_launch(void* const* d_in, const int* in_sizes, int n_in,
                              void* d_out, int out_size, void* d_ws, size_t ws_size,
                              hipStream_t stream) {
    (void)in_sizes; (void)n_in; (void)out_size; (void)ws_size;
    const float* x     = (const float*)d_in[0];   // (8, 4096, 1024) f32
    const float* alpha = (const float*)d_in[1];   // (1024,) f32
    const float* beta  = (const float*)d_in[2];   // (1024,) f32
    float* out     = (float*)d_out;
    float* mean_ws = (float*)d_ws;                // 4096 floats
    float* rstd_ws = mean_ws + SS;                // 4096 floats

    hipLaunchKernelGGL(stats_norm0_kernel, dim3(SS), dim3(64), 0, stream,
                       x, alpha, beta, out, mean_ws, rstd_ws);
    hipLaunchKernelGGL(norm_rest_kernel, dim3(NBLK), dim3(256), 0, stream,
                       x, alpha, beta, mean_ws, rstd_ws, out);
}